// Round 5
// baseline (8191.756 us; speedup 1.0000x reference)
//
#include <hip/hip_runtime.h>
#include <hip/hip_bf16.h>
#include <cmath>

#define BATCH 64
#define SEQ   512
#define ISZ   512
#define HSZ   1024

// Persistent-kernel partition: 64 WGs = 4 batch-groups x 16 col-groups.
// BARRIER-FREE per-wave pipeline. Each wave computes full K=1024 for ONE
// 16-col n-tile, so output columns are wholly wave-owned and the inter-wave
// LDS reduce (and its two __syncthreads joins) is eliminated. Handoff is
// per-wave: 64 flags per batch group. Producer wave publishes its flag with
// a RELEASE store (emits wave-granular s_waitcnt vmcnt(0) first -> provably
// drains all 64 lanes' hn stores). Consumer waves poll all 64 flags with
// ACQUIRE loads (real ordering edge for the subsequent h loads — the
// primitive round-2's relaxed spin lacked). Zero __syncthreads in the loop.
#define NWG 64
#define BT  16   // batches per WG (one 16-row MFMA m-tile)
#define NT  64   // columns per WG (4 waves x one 16-col n-tile each)
#define GRP_WGS 16
#define FLAG_STRIDE 32   // ints: 128B line spacing per flag

typedef __attribute__((ext_vector_type(8))) short short8;   // 8 bf16 (A/B frag)
typedef __attribute__((ext_vector_type(4))) float floatx4;  // C/D frag
typedef unsigned long long ull;

union Frag { short8 s8; ull u2[2]; };

__device__ __forceinline__ ushort f2bf(float f) {
  unsigned u = __builtin_bit_cast(unsigned, f);
  unsigned r = (u + 0x7fffu + ((u >> 16) & 1u)) >> 16;
  return (ushort)r;
}
__device__ __forceinline__ ull pack4(float a, float b, float c, float d) {
  unsigned lo = (unsigned)f2bf(a) | ((unsigned)f2bf(b) << 16);
  unsigned hi = (unsigned)f2bf(c) | ((unsigned)f2bf(d) << 16);
  return (ull)lo | ((ull)hi << 32);
}

// Fast tanh via v_exp_f32/v_rcp_f32; |err| ~1e-6, clamp keeps it NaN-safe.
__device__ __forceinline__ float fast_tanh(float x) {
  float cx = fminf(20.f, fmaxf(-20.f, x));
  float e  = __builtin_amdgcn_exp2f(cx * 2.8853900817779268f);  // 2*log2(e)
  return (e - 1.f) * __builtin_amdgcn_rcpf(e + 1.f);
}

// ---------------------------------------------------------------------------
// Kernel 1: x_proj = inputs @ W_xh + b_h  (fp32, 128x128 tile, 8x8 acc/thread)
// (unchanged from the passing round-3 version)
// ---------------------------------------------------------------------------
__global__ __launch_bounds__(256) void xproj_gemm(
    const float* __restrict__ A,     // (32768, 512) row-major
    const float* __restrict__ Bw,    // (512, 1024) row-major
    const float* __restrict__ bias,  // (1024,)
    float* __restrict__ C) {         // (32768, 1024)
  __shared__ float As[16][132];      // [k][m], padded
  __shared__ float Bs[16][128];      // [k][n]

  const int tid = threadIdx.x;
  const int n0 = blockIdx.x * 128;
  const int m0 = blockIdx.y * 128;
  const int ty = (tid >> 4) & 15;    // 0..15
  const int tx = tid & 15;           // 0..15

  float acc[8][8] = {};

  const int ar = tid >> 2;           // 0..63  A row within half-tile
  const int ak = (tid & 3) << 2;     // 0,4,8,12
  const int bk = tid >> 5;           // 0..7   B k within half
  const int bn = (tid & 31) << 2;    // 0..124

  for (int kt = 0; kt < ISZ; kt += 16) {
    __syncthreads();
#pragma unroll
    for (int h = 0; h < 2; ++h) {
      int row = ar + h * 64;
      float4 v = *(const float4*)&A[(size_t)(m0 + row) * ISZ + kt + ak];
      As[ak + 0][row] = v.x;
      As[ak + 1][row] = v.y;
      As[ak + 2][row] = v.z;
      As[ak + 3][row] = v.w;
    }
#pragma unroll
    for (int h = 0; h < 2; ++h) {
      int k = bk + h * 8;
      float4 v = *(const float4*)&Bw[(size_t)(kt + k) * HSZ + n0 + bn];
      *(float4*)&Bs[k][bn] = v;
    }
    __syncthreads();

#pragma unroll
    for (int k = 0; k < 16; ++k) {
      const float4* Ar4 = (const float4*)&As[k][0];
      const float4* Br4 = (const float4*)&Bs[k][0];
      float4 a0 = Ar4[ty];
      float4 a1 = Ar4[16 + ty];
      float4 b0 = Br4[tx];
      float4 b1 = Br4[16 + tx];
      float av[8] = {a0.x, a0.y, a0.z, a0.w, a1.x, a1.y, a1.z, a1.w};
      float bv[8] = {b0.x, b0.y, b0.z, b0.w, b1.x, b1.y, b1.z, b1.w};
#pragma unroll
      for (int i = 0; i < 8; ++i)
#pragma unroll
        for (int j = 0; j < 8; ++j)
          acc[i][j] = fmaf(av[i], bv[j], acc[i][j]);
    }
  }

  const float4 bv0 = *(const float4*)&bias[n0 + tx * 4];
  const float4 bv1 = *(const float4*)&bias[n0 + 64 + tx * 4];
#pragma unroll
  for (int i = 0; i < 8; ++i) {
    int row = m0 + ((i < 4) ? (ty * 4 + i) : (64 + ty * 4 + (i - 4)));
    float4 o0, o1;
    o0.x = acc[i][0] + bv0.x;  o0.y = acc[i][1] + bv0.y;
    o0.z = acc[i][2] + bv0.z;  o0.w = acc[i][3] + bv0.w;
    o1.x = acc[i][4] + bv1.x;  o1.y = acc[i][5] + bv1.y;
    o1.z = acc[i][6] + bv1.z;  o1.w = acc[i][7] + bv1.w;
    *(float4*)&C[(size_t)row * HSZ + n0 + tx * 4] = o0;
    *(float4*)&C[(size_t)row * HSZ + n0 + 64 + tx * 4] = o1;
  }
}

// ---------------------------------------------------------------------------
// Kernel 2: init the 256 per-wave step flags to -1 ("nothing published")
// ---------------------------------------------------------------------------
__global__ void init_cnt(int* c) { c[threadIdx.x * FLAG_STRIDE] = -1; }

// ---------------------------------------------------------------------------
// Kernel 3: persistent RNN recurrence, barrier-free wave pipeline.
// flag[gb*64 + gn*4 + w] == s  <=>  wave (gn,w)'s h_s n-tile is at LLC.
// Per wave, per step t:
//   1. lanes 0..63 poll the group's 64 flags (ACQUIRE) until all >= t
//   2. load full-K A-frags (32 kc x 16B/lane, sc1 relaxed)
//   3. 32 MFMA into 4 interleaved acc chains; sum chains
//   4. wave-private LDS transpose (C-frag -> row-major), + xp, fast_tanh
//   5. hn tile store (sc1 relaxed, 8B/lane)
//   6. lane 0: RELEASE flag store = t+1  (emits wave-granular vmcnt(0) drain
//      first -> all 64 lanes' step-t stores complete before flag visible)
//   7. out store + next-xp prefetch (wave-private, off the critical path)
// Overwrite safety: wave observes ALL 64 flags >= t (acquire) before any
// access of step t; flag(Y,w')>=t => that wave completed step t-1 incl. its
// h_{t-1} loads => overwriting buf[(t+1)&1] (holding h_{t-1}) is safe.
// ---------------------------------------------------------------------------
__global__ __launch_bounds__(256, 1) void rnn_persistent(
    const float* __restrict__ h_prev,   // (64, 1024) fp32
    const float* __restrict__ W,        // (1024, 1024) fp32
    float* __restrict__ out,            // (64, 512, 1024) fp32 (xp in, h out)
    ull* __restrict__ h_a,              // (64, 256) bf16x4 ping
    ull* __restrict__ h_b,              // (64, 256) bf16x4 pong
    int* __restrict__ cnt) {            // 256 step flags, 128B apart
  extern __shared__ char smem[];
  ushort* Wfrag = (ushort*)smem;                 // 32kc*4nt*64lane*8 = 128 KB
  float*  scrAll = (float*)(smem + 131072);      // 4 waves * 16*20 floats

  const int tid = threadIdx.x;
  const int gb = blockIdx.x & 3;       // batch group 0..3
  const int gn = blockIdx.x >> 2;      // col group 0..15
  const int b0 = gb * BT;
  const int n0 = gn * NT;

  // ---- one-time: W_hh column slice -> bf16 fragments in LDS ----
  for (int it = tid; it < 1024 * 16; it += 256) {
    int k  = it >> 4;
    int c4 = (it & 15) << 2;
    float4 w4 = *(const float4*)&W[(size_t)k * HSZ + n0 + c4];
    int kc = k >> 5, j = k & 7, q = (k >> 3) & 3;
    float wv[4] = {w4.x, w4.y, w4.z, w4.w};
#pragma unroll
    for (int e = 0; e < 4; ++e) {
      int n = c4 + e;
      int nt = n >> 4;
      int lane = q * 16 + (n & 15);
      Wfrag[((kc * 4 + nt) * 64 + lane) * 8 + j] = f2bf(wv[e]);
    }
  }

  // ---- one-time: OWN slice of h0 = bf16(h_prev) -> h_a (sc1) ----
  {
    int r  = tid >> 4;                 // 0..15 row
    int c  = tid & 15;                 // 0..15 ull col within slice
    int col4 = n0 + c * 4;
    float4 v = *(const float4*)&h_prev[(size_t)(b0 + r) * HSZ + col4];
    __hip_atomic_store(&h_a[(size_t)(b0 + r) * 256 + (col4 >> 2)],
                       pack4(v.x, v.y, v.z, v.w),
                       __ATOMIC_RELAXED, __HIP_MEMORY_SCOPE_AGENT);
  }

  const int w  = tid >> 6;             // wave 0..3 -> n-tile w
  const int l  = tid & 63;
  const int bRow = b0 + (l & 15);      // A-frag row (batch)
  const int q2 = ((l >> 4) & 3) * 2;   // frag k sub-offset in 8B units

  float* scr = scrAll + w * 320;       // wave-private 16x20 f32 scratch

  // flags
  int* myFlag   = cnt + (gb * 64 + gn * 4 + w) * FLAG_STRIDE;
  int* pollFlag = cnt + (gb * 64 + l) * FLAG_STRIDE;   // lane l <-> flag l

  // epilogue mapping: lane l -> row R=l>>2, cols 16w+(l&3)*4 .. +4
  const int R   = l >> 2;
  const int C4  = w * 16 + (l & 3) * 4;
  const size_t obase = ((size_t)(b0 + R) * SEQ) * HSZ + n0 + C4;
  const size_t hnIdx = (size_t)(b0 + R) * 256 + ((n0 + C4) >> 2);

  ull* hc = h_a;
  ull* hn = h_b;

  // prefetch xp for t=0 (no dependency on h)
  float4 xp = *(const float4*)&out[obase];

  // publish h0: one-time barrier drains all threads' h0 stores (vmcnt0),
  // then each wave's lane 0 releases its flag (release = belt-and-braces).
  __syncthreads();
  if (l == 0)
    __hip_atomic_store(myFlag, 0, __ATOMIC_RELEASE, __HIP_MEMORY_SCOPE_AGENT);

  for (int t = 0; t < SEQ; ++t) {
    // ---- 1. acquire: all 64 group flags >= t (lane l polls flag l) ----
    while (__hip_atomic_load(pollFlag, __ATOMIC_ACQUIRE,
                             __HIP_MEMORY_SCOPE_AGENT) < t)
      __builtin_amdgcn_s_sleep(1);

    // ---- 2. load full-K A-frags: 32 kc x 2 ull per lane (sc1) ----
    Frag af[32];
    const ull* hq = hc + (size_t)bRow * 256;
#pragma unroll
    for (int i = 0; i < 32; ++i) {
      const int off = i * 8 + q2;
      af[i].u2[0] = __hip_atomic_load(hq + off, __ATOMIC_RELAXED,
                                      __HIP_MEMORY_SCOPE_AGENT);
      af[i].u2[1] = __hip_atomic_load(hq + off + 1, __ATOMIC_RELAXED,
                                      __HIP_MEMORY_SCOPE_AGENT);
    }

    // ---- 3. 32 MFMA, 4 interleaved acc chains (dep-latency / 4) ----
    floatx4 acc[4] = {floatx4{0.f, 0.f, 0.f, 0.f}, floatx4{0.f, 0.f, 0.f, 0.f},
                      floatx4{0.f, 0.f, 0.f, 0.f}, floatx4{0.f, 0.f, 0.f, 0.f}};
#pragma unroll
    for (int i = 0; i < 32; ++i) {
      short8 b8 = *(const short8*)&Wfrag[((i * 4 + w) * 64 + l) * 8];
      acc[i & 3] = __builtin_amdgcn_mfma_f32_16x16x32_bf16(af[i].s8, b8, acc[i & 3], 0, 0, 0);
    }
    floatx4 hs = acc[0] + acc[1] + acc[2] + acc[3];

    // ---- 4. wave-private transpose: C-frag (row=(l>>4)*4+r, col=l&15) ----
    {
      const int rbase = (l >> 4) * 4;
      const int cbase = l & 15;
#pragma unroll
      for (int r = 0; r < 4; ++r)
        scr[(rbase + r) * 20 + cbase] = hs[r];
    }
    // same-wave ds_write -> ds_read: compiler inserts lgkmcnt wait
    float4 cv = *(const float4*)&scr[R * 20 + (l & 3) * 4];
    float4 hv;
    hv.x = fast_tanh(cv.x + xp.x);
    hv.y = fast_tanh(cv.y + xp.y);
    hv.z = fast_tanh(cv.z + xp.z);
    hv.w = fast_tanh(cv.w + xp.w);

    // ---- 5. hn tile store (8B per lane, sc1) ----
    __hip_atomic_store(&hn[hnIdx], pack4(hv.x, hv.y, hv.z, hv.w),
                       __ATOMIC_RELAXED, __HIP_MEMORY_SCOPE_AGENT);

    // ---- 6. release flag: vmcnt(0) drain (wave-granular) then store ----
    if (l == 0)
      __hip_atomic_store(myFlag, t + 1, __ATOMIC_RELEASE,
                         __HIP_MEMORY_SCOPE_AGENT);

    // ---- 7. wave-private work, off the inter-WG critical path ----
    *(float4*)&out[obase + (size_t)t * HSZ] = hv;          // h_t -> out (HBM)
    if (t + 1 < SEQ)                                       // next xp prefetch
      xp = *(const float4*)&out[obase + (size_t)(t + 1) * HSZ];

    ull* tmp = hc; hc = hn; hn = tmp;
  }
}

// ---------------------------------------------------------------------------
extern "C" void kernel_launch(void* const* d_in, const int* in_sizes, int n_in,
                              void* d_out, int out_size, void* d_ws, size_t ws_size,
                              hipStream_t stream) {
  const float* inputs = (const float*)d_in[0];  // (64, 512, 512)
  const float* h_prev = (const float*)d_in[1];  // (64, 1024)
  const float* W_xh   = (const float*)d_in[2];  // (512, 1024)
  const float* W_hh   = (const float*)d_in[3];  // (1024, 1024)
  const float* b_h    = (const float*)d_in[4];  // (1024,)
  float* out = (float*)d_out;                   // (64, 512, 1024)

  int* cnt = (int*)d_ws;                        // 256 flags, 128B apart (32 KB)
  ull* h_a = (ull*)((char*)d_ws + 32768);
  ull* h_b = h_a + BATCH * 256;                 // 128 KB each

  // 1. x_proj -> d_out
  dim3 g1(HSZ / 128, (BATCH * SEQ) / 128);      // (8, 256)
  xproj_gemm<<<g1, 256, 0, stream>>>(inputs, W_xh, b_h, out);

  // 2. init per-wave flags to -1
  init_cnt<<<1, 256, 0, stream>>>(cnt);

  // 3. persistent recurrence (133 KB dynamic LDS -> 1 WG/CU)
  const int smem_bytes = 131072 + 4 * 16 * 20 * (int)sizeof(float);  // 136192
  hipFuncSetAttribute((const void*)rnn_persistent,
                      hipFuncAttributeMaxDynamicSharedMemorySize, smem_bytes);
  rnn_persistent<<<NWG, 256, smem_bytes, stream>>>(h_prev, W_hh, out, h_a, h_b, cnt);
}

// Round 6
// 5199.882 us; speedup vs baseline: 1.5754x; 1.5754x over previous
//
#include <hip/hip_runtime.h>
#include <hip/hip_bf16.h>
#include <cmath>

#define BATCH 64
#define SEQ   512
#define ISZ   512
#define HSZ   1024

// Persistent-kernel partition: 64 WGs = 4 batch-groups x 16 col-groups.
// BARRIER-FREE per-wave pipeline (structure proven correct in round 5).
// Each wave computes full K=1024 for ONE 16-col n-tile; output columns are
// wholly wave-owned; zero __syncthreads in the loop.
//
// Sync primitives (this round): the round-5 acquire/release atomics emitted
// buffer_inv per POLL and buffer_wbl2 per RELEASE (L1/L2 invalidate +
// writeback) -> 4.8x slowdown. Replaced with the fence-free mechanism that
// passed rounds 0/1/3: all cross-WG data uses RELAXED agent-scope atomics
// (sc0+sc1: bypass L1/L2, LLC-coherent); producer drains with inline-asm
// s_waitcnt vmcnt(0) (wave-granular store-ack, no cache ops) before the
// relaxed flag store; consumer uses a compiler barrier + sched_barrier after
// the relaxed spin so no h load is hoisted above flag observation (the
// round-2 failure hole). HW issue is in-order per wave -> loads issued after
// spin exit read LLC state that already contains the producer's stores.
#define NWG 64
#define BT  16   // batches per WG (one 16-row MFMA m-tile)
#define NT  64   // columns per WG (4 waves x one 16-col n-tile each)
#define GRP_WGS 16
#define FLAG_STRIDE 32   // ints: 128B line spacing per flag

typedef __attribute__((ext_vector_type(8))) short short8;   // 8 bf16 (A/B frag)
typedef __attribute__((ext_vector_type(4))) float floatx4;  // C/D frag
typedef unsigned long long ull;

union Frag { short8 s8; ull u2[2]; };

__device__ __forceinline__ ushort f2bf(float f) {
  unsigned u = __builtin_bit_cast(unsigned, f);
  unsigned r = (u + 0x7fffu + ((u >> 16) & 1u)) >> 16;
  return (ushort)r;
}
__device__ __forceinline__ ull pack4(float a, float b, float c, float d) {
  unsigned lo = (unsigned)f2bf(a) | ((unsigned)f2bf(b) << 16);
  unsigned hi = (unsigned)f2bf(c) | ((unsigned)f2bf(d) << 16);
  return (ull)lo | ((ull)hi << 32);
}

// Fast tanh via v_exp_f32/v_rcp_f32; |err| ~1e-6, clamp keeps it NaN-safe.
__device__ __forceinline__ float fast_tanh(float x) {
  float cx = fminf(20.f, fmaxf(-20.f, x));
  float e  = __builtin_amdgcn_exp2f(cx * 2.8853900817779268f);  // 2*log2(e)
  return (e - 1.f) * __builtin_amdgcn_rcpf(e + 1.f);
}

// ---------------------------------------------------------------------------
// Kernel 1: x_proj = inputs @ W_xh + b_h  (fp32, 128x128 tile, 8x8 acc/thread)
// (unchanged from the passing round-3 version)
// ---------------------------------------------------------------------------
__global__ __launch_bounds__(256) void xproj_gemm(
    const float* __restrict__ A,     // (32768, 512) row-major
    const float* __restrict__ Bw,    // (512, 1024) row-major
    const float* __restrict__ bias,  // (1024,)
    float* __restrict__ C) {         // (32768, 1024)
  __shared__ float As[16][132];      // [k][m], padded
  __shared__ float Bs[16][128];      // [k][n]

  const int tid = threadIdx.x;
  const int n0 = blockIdx.x * 128;
  const int m0 = blockIdx.y * 128;
  const int ty = (tid >> 4) & 15;    // 0..15
  const int tx = tid & 15;           // 0..15

  float acc[8][8] = {};

  const int ar = tid >> 2;           // 0..63  A row within half-tile
  const int ak = (tid & 3) << 2;     // 0,4,8,12
  const int bk = tid >> 5;           // 0..7   B k within half
  const int bn = (tid & 31) << 2;    // 0..124

  for (int kt = 0; kt < ISZ; kt += 16) {
    __syncthreads();
#pragma unroll
    for (int h = 0; h < 2; ++h) {
      int row = ar + h * 64;
      float4 v = *(const float4*)&A[(size_t)(m0 + row) * ISZ + kt + ak];
      As[ak + 0][row] = v.x;
      As[ak + 1][row] = v.y;
      As[ak + 2][row] = v.z;
      As[ak + 3][row] = v.w;
    }
#pragma unroll
    for (int h = 0; h < 2; ++h) {
      int k = bk + h * 8;
      float4 v = *(const float4*)&Bw[(size_t)(kt + k) * HSZ + n0 + bn];
      *(float4*)&Bs[k][bn] = v;
    }
    __syncthreads();

#pragma unroll
    for (int k = 0; k < 16; ++k) {
      const float4* Ar4 = (const float4*)&As[k][0];
      const float4* Br4 = (const float4*)&Bs[k][0];
      float4 a0 = Ar4[ty];
      float4 a1 = Ar4[16 + ty];
      float4 b0 = Br4[tx];
      float4 b1 = Br4[16 + tx];
      float av[8] = {a0.x, a0.y, a0.z, a0.w, a1.x, a1.y, a1.z, a1.w};
      float bv[8] = {b0.x, b0.y, b0.z, b0.w, b1.x, b1.y, b1.z, b1.w};
#pragma unroll
      for (int i = 0; i < 8; ++i)
#pragma unroll
        for (int j = 0; j < 8; ++j)
          acc[i][j] = fmaf(av[i], bv[j], acc[i][j]);
    }
  }

  const float4 bv0 = *(const float4*)&bias[n0 + tx * 4];
  const float4 bv1 = *(const float4*)&bias[n0 + 64 + tx * 4];
#pragma unroll
  for (int i = 0; i < 8; ++i) {
    int row = m0 + ((i < 4) ? (ty * 4 + i) : (64 + ty * 4 + (i - 4)));
    float4 o0, o1;
    o0.x = acc[i][0] + bv0.x;  o0.y = acc[i][1] + bv0.y;
    o0.z = acc[i][2] + bv0.z;  o0.w = acc[i][3] + bv0.w;
    o1.x = acc[i][4] + bv1.x;  o1.y = acc[i][5] + bv1.y;
    o1.z = acc[i][6] + bv1.z;  o1.w = acc[i][7] + bv1.w;
    *(float4*)&C[(size_t)row * HSZ + n0 + tx * 4] = o0;
    *(float4*)&C[(size_t)row * HSZ + n0 + 64 + tx * 4] = o1;
  }
}

// ---------------------------------------------------------------------------
// Kernel 2: init the 256 per-wave step flags to -1 ("nothing published")
// ---------------------------------------------------------------------------
__global__ void init_cnt(int* c) { c[threadIdx.x * FLAG_STRIDE] = -1; }

// ---------------------------------------------------------------------------
// Kernel 3: persistent RNN recurrence, barrier-free wave pipeline.
// flag[gb*64 + gn*4 + w] == s  <=>  wave (gn,w)'s h_s n-tile is at LLC.
// Per wave, per step t:
//   1. lanes 0..63 poll the group's 64 flags (RELAXED) until all >= t;
//      then compiler barrier + sched_barrier(0): no h load crosses the spin
//   2. load full-K A-frags (32 kc x 16B/lane, relaxed sc1 -> LLC, no stale
//      cache possible since sc0+sc1 bypass L1/L2)
//   3. 32 MFMA into 4 interleaved acc chains; sum chains
//   4. wave-private LDS transpose (C-frag -> row-major), + xp, fast_tanh
//   5. hn tile store (relaxed sc1, 8B/lane)
//   6. inline-asm s_waitcnt vmcnt(0) ("memory"): all 64 lanes' step-t stores
//      acked at LLC, no cache-maintenance ops; then lane 0 stores flag=t+1
//      (relaxed). Same drain mechanism as the passing rounds 0/1/3
//      (__syncthreads' vmcnt(0)), minus the barrier.
//   7. out store + next-xp prefetch (wave-private, off the critical path)
// Overwrite safety: wave observes ALL 64 flags >= t before any access of
// step t; flag(Y,w')>=t => that wave completed step t-1 incl. its h_{t-1}
// loads (vmcnt counts loads too) => overwriting buf[(t+1)&1] is safe.
// ---------------------------------------------------------------------------
__global__ __launch_bounds__(256, 1) void rnn_persistent(
    const float* __restrict__ h_prev,   // (64, 1024) fp32
    const float* __restrict__ W,        // (1024, 1024) fp32
    float* __restrict__ out,            // (64, 512, 1024) fp32 (xp in, h out)
    ull* __restrict__ h_a,              // (64, 256) bf16x4 ping
    ull* __restrict__ h_b,              // (64, 256) bf16x4 pong
    int* __restrict__ cnt) {            // 256 step flags, 128B apart
  extern __shared__ char smem[];
  ushort* Wfrag = (ushort*)smem;                 // 32kc*4nt*64lane*8 = 128 KB
  float*  scrAll = (float*)(smem + 131072);      // 4 waves * 16*20 floats

  const int tid = threadIdx.x;
  const int gb = blockIdx.x & 3;       // batch group 0..3
  const int gn = blockIdx.x >> 2;      // col group 0..15
  const int b0 = gb * BT;
  const int n0 = gn * NT;

  // ---- one-time: W_hh column slice -> bf16 fragments in LDS ----
  for (int it = tid; it < 1024 * 16; it += 256) {
    int k  = it >> 4;
    int c4 = (it & 15) << 2;
    float4 w4 = *(const float4*)&W[(size_t)k * HSZ + n0 + c4];
    int kc = k >> 5, j = k & 7, q = (k >> 3) & 3;
    float wv[4] = {w4.x, w4.y, w4.z, w4.w};
#pragma unroll
    for (int e = 0; e < 4; ++e) {
      int n = c4 + e;
      int nt = n >> 4;
      int lane = q * 16 + (n & 15);
      Wfrag[((kc * 4 + nt) * 64 + lane) * 8 + j] = f2bf(wv[e]);
    }
  }

  // ---- one-time: OWN slice of h0 = bf16(h_prev) -> h_a (sc1) ----
  {
    int r  = tid >> 4;                 // 0..15 row
    int c  = tid & 15;                 // 0..15 ull col within slice
    int col4 = n0 + c * 4;
    float4 v = *(const float4*)&h_prev[(size_t)(b0 + r) * HSZ + col4];
    __hip_atomic_store(&h_a[(size_t)(b0 + r) * 256 + (col4 >> 2)],
                       pack4(v.x, v.y, v.z, v.w),
                       __ATOMIC_RELAXED, __HIP_MEMORY_SCOPE_AGENT);
  }

  const int w  = tid >> 6;             // wave 0..3 -> n-tile w
  const int l  = tid & 63;
  const int bRow = b0 + (l & 15);      // A-frag row (batch)
  const int q2 = ((l >> 4) & 3) * 2;   // frag k sub-offset in 8B units

  float* scr = scrAll + w * 320;       // wave-private 16x20 f32 scratch

  // flags
  int* myFlag   = cnt + (gb * 64 + gn * 4 + w) * FLAG_STRIDE;
  int* pollFlag = cnt + (gb * 64 + l) * FLAG_STRIDE;   // lane l <-> flag l

  // epilogue mapping: lane l -> row R=l>>2, cols 16w+(l&3)*4 .. +4
  const int R   = l >> 2;
  const int C4  = w * 16 + (l & 3) * 4;
  const size_t obase = ((size_t)(b0 + R) * SEQ) * HSZ + n0 + C4;
  const size_t hnIdx = (size_t)(b0 + R) * 256 + ((n0 + C4) >> 2);

  ull* hc = h_a;
  ull* hn = h_b;

  // prefetch xp for t=0 (no dependency on h)
  float4 xp = *(const float4*)&out[obase];

  // publish h0: the one-time barrier drains all threads' h0 stores (vmcnt0)
  // — proven release mechanism — then each wave's lane 0 stores its flag.
  __syncthreads();
  if (l == 0)
    __hip_atomic_store(myFlag, 0, __ATOMIC_RELAXED, __HIP_MEMORY_SCOPE_AGENT);

  for (int t = 0; t < SEQ; ++t) {
    // ---- 1. spin: all 64 group flags >= t (lane l polls flag l) ----
    while (__hip_atomic_load(pollFlag, __ATOMIC_RELAXED,
                             __HIP_MEMORY_SCOPE_AGENT) < t)
      __builtin_amdgcn_s_sleep(1);
    // Compiler fence: nothing below (the h loads!) may be hoisted above the
    // spin — IR-level (asm memory clobber) and MIR-level (sched_barrier).
    asm volatile("" ::: "memory");
    __builtin_amdgcn_sched_barrier(0);

    // ---- 2. load full-K A-frags: 32 kc x 2 ull per lane (relaxed sc1) ----
    Frag af[32];
    const ull* hq = hc + (size_t)bRow * 256;
#pragma unroll
    for (int i = 0; i < 32; ++i) {
      const int off = i * 8 + q2;
      af[i].u2[0] = __hip_atomic_load(hq + off, __ATOMIC_RELAXED,
                                      __HIP_MEMORY_SCOPE_AGENT);
      af[i].u2[1] = __hip_atomic_load(hq + off + 1, __ATOMIC_RELAXED,
                                      __HIP_MEMORY_SCOPE_AGENT);
    }

    // ---- 3. 32 MFMA, 4 interleaved acc chains (dep-latency / 4) ----
    floatx4 acc[4] = {floatx4{0.f, 0.f, 0.f, 0.f}, floatx4{0.f, 0.f, 0.f, 0.f},
                      floatx4{0.f, 0.f, 0.f, 0.f}, floatx4{0.f, 0.f, 0.f, 0.f}};
#pragma unroll
    for (int i = 0; i < 32; ++i) {
      short8 b8 = *(const short8*)&Wfrag[((i * 4 + w) * 64 + l) * 8];
      acc[i & 3] = __builtin_amdgcn_mfma_f32_16x16x32_bf16(af[i].s8, b8, acc[i & 3], 0, 0, 0);
    }
    floatx4 hs = acc[0] + acc[1] + acc[2] + acc[3];

    // ---- 4. wave-private transpose: C-frag (row=(l>>4)*4+r, col=l&15) ----
    {
      const int rbase = (l >> 4) * 4;
      const int cbase = l & 15;
#pragma unroll
      for (int r = 0; r < 4; ++r)
        scr[(rbase + r) * 20 + cbase] = hs[r];
    }
    // same-wave ds_write -> ds_read: compiler inserts lgkmcnt wait
    float4 cv = *(const float4*)&scr[R * 20 + (l & 3) * 4];
    float4 hv;
    hv.x = fast_tanh(cv.x + xp.x);
    hv.y = fast_tanh(cv.y + xp.y);
    hv.z = fast_tanh(cv.z + xp.z);
    hv.w = fast_tanh(cv.w + xp.w);

    // ---- 5. hn tile store (8B per lane, relaxed sc1 -> LLC) ----
    __hip_atomic_store(&hn[hnIdx], pack4(hv.x, hv.y, hv.z, hv.w),
                       __ATOMIC_RELAXED, __HIP_MEMORY_SCOPE_AGENT);

    // ---- 6. wave-granular release: drain all 64 lanes' stores (no cache
    //         ops), then lane 0 publishes the flag (relaxed) ----
    asm volatile("s_waitcnt vmcnt(0)" ::: "memory");
    if (l == 0)
      __hip_atomic_store(myFlag, t + 1, __ATOMIC_RELAXED,
                         __HIP_MEMORY_SCOPE_AGENT);

    // ---- 7. wave-private work, off the inter-WG critical path ----
    *(float4*)&out[obase + (size_t)t * HSZ] = hv;          // h_t -> out (HBM)
    if (t + 1 < SEQ)                                       // next xp prefetch
      xp = *(const float4*)&out[obase + (size_t)(t + 1) * HSZ];

    ull* tmp = hc; hc = hn; hn = tmp;
  }
}

// ---------------------------------------------------------------------------
extern "C" void kernel_launch(void* const* d_in, const int* in_sizes, int n_in,
                              void* d_out, int out_size, void* d_ws, size_t ws_size,
                              hipStream_t stream) {
  const float* inputs = (const float*)d_in[0];  // (64, 512, 512)
  const float* h_prev = (const float*)d_in[1];  // (64, 1024)
  const float* W_xh   = (const float*)d_in[2];  // (512, 1024)
  const float* W_hh   = (const float*)d_in[3];  // (1024, 1024)
  const float* b_h    = (const float*)d_in[4];  // (1024,)
  float* out = (float*)d_out;                   // (64, 512, 1024)

  int* cnt = (int*)d_ws;                        // 256 flags, 128B apart (32 KB)
  ull* h_a = (ull*)((char*)d_ws + 32768);
  ull* h_b = h_a + BATCH * 256;                 // 128 KB each

  // 1. x_proj -> d_out
  dim3 g1(HSZ / 128, (BATCH * SEQ) / 128);      // (8, 256)
  xproj_gemm<<<g1, 256, 0, stream>>>(inputs, W_xh, b_h, out);

  // 2. init per-wave flags to -1
  init_cnt<<<1, 256, 0, stream>>>(cnt);

  // 3. persistent recurrence (133 KB dynamic LDS -> 1 WG/CU)
  const int smem_bytes = 131072 + 4 * 16 * 20 * (int)sizeof(float);  // 136192
  hipFuncSetAttribute((const void*)rnn_persistent,
                      hipFuncAttributeMaxDynamicSharedMemorySize, smem_bytes);
  rnn_persistent<<<NWG, 256, smem_bytes, stream>>>(h_prev, W_hh, out, h_a, h_b, cnt);
}

// Round 7
// 1638.871 us; speedup vs baseline: 4.9984x; 3.1728x over previous
//
#include <hip/hip_runtime.h>
#include <hip/hip_bf16.h>
#include <cmath>

#define BATCH 64
#define SEQ   512
#define ISZ   512
#define HSZ   1024

// Persistent-kernel partition: 64 WGs = 4 batch-groups x 16 col-groups.
// ROUND-3 SKELETON (proven 1614 us): K-split across 4 waves, Cred LDS
// reduce, per-WG flags, __syncthreads-drain release. Two changes:
//  (1) h exchange buffer in MFMA A-FRAGMENT layout [gb][kc][lane][16B] ->
//      consumer loads are coalesced (1KB/instr) instead of 2048B-stride
//      8B scatter (round-6 lesson: scattered sc1 loads dominate).
//  (2) closing barrier removed: EVERY wave polls the 16 group flags
//      (lanes l&15), then asm-fence + sched_barrier before the h loads —
//      the relaxed-spin->fence->relaxed-load primitive proven correct in
//      rounds 5/6. One fewer barrier on the critical path.
#define NWG 64
#define BT  16   // batches per WG (one 16-row MFMA m-tile)
#define NT  64   // columns per WG (four 16-col MFMA n-tiles)
#define GRP_WGS 16
#define FLAG_STRIDE 32   // ints: 128B line spacing per flag

typedef __attribute__((ext_vector_type(8))) short short8;   // 8 bf16 (A/B frag)
typedef __attribute__((ext_vector_type(4))) float floatx4;  // C/D frag
typedef unsigned long long ull;

union Frag { short8 s8; ull u2[2]; };

__device__ __forceinline__ ushort f2bf(float f) {
  unsigned u = __builtin_bit_cast(unsigned, f);
  unsigned r = (u + 0x7fffu + ((u >> 16) & 1u)) >> 16;
  return (ushort)r;
}
__device__ __forceinline__ ull pack4(float a, float b, float c, float d) {
  unsigned lo = (unsigned)f2bf(a) | ((unsigned)f2bf(b) << 16);
  unsigned hi = (unsigned)f2bf(c) | ((unsigned)f2bf(d) << 16);
  return (ull)lo | ((ull)hi << 32);
}

// Fast tanh via v_exp_f32/v_rcp_f32; |err| ~1e-6, clamp keeps it NaN-safe.
__device__ __forceinline__ float fast_tanh(float x) {
  float cx = fminf(20.f, fmaxf(-20.f, x));
  float e  = __builtin_amdgcn_exp2f(cx * 2.8853900817779268f);  // 2*log2(e)
  return (e - 1.f) * __builtin_amdgcn_rcpf(e + 1.f);
}

// ---------------------------------------------------------------------------
// Kernel 1: x_proj = inputs @ W_xh + b_h  (fp32, 128x128 tile, 8x8 acc/thread)
// (unchanged from the passing round-3 version)
// ---------------------------------------------------------------------------
__global__ __launch_bounds__(256) void xproj_gemm(
    const float* __restrict__ A,     // (32768, 512) row-major
    const float* __restrict__ Bw,    // (512, 1024) row-major
    const float* __restrict__ bias,  // (1024,)
    float* __restrict__ C) {         // (32768, 1024)
  __shared__ float As[16][132];      // [k][m], padded
  __shared__ float Bs[16][128];      // [k][n]

  const int tid = threadIdx.x;
  const int n0 = blockIdx.x * 128;
  const int m0 = blockIdx.y * 128;
  const int ty = (tid >> 4) & 15;    // 0..15
  const int tx = tid & 15;           // 0..15

  float acc[8][8] = {};

  const int ar = tid >> 2;           // 0..63  A row within half-tile
  const int ak = (tid & 3) << 2;     // 0,4,8,12
  const int bk = tid >> 5;           // 0..7   B k within half
  const int bn = (tid & 31) << 2;    // 0..124

  for (int kt = 0; kt < ISZ; kt += 16) {
    __syncthreads();
#pragma unroll
    for (int h = 0; h < 2; ++h) {
      int row = ar + h * 64;
      float4 v = *(const float4*)&A[(size_t)(m0 + row) * ISZ + kt + ak];
      As[ak + 0][row] = v.x;
      As[ak + 1][row] = v.y;
      As[ak + 2][row] = v.z;
      As[ak + 3][row] = v.w;
    }
#pragma unroll
    for (int h = 0; h < 2; ++h) {
      int k = bk + h * 8;
      float4 v = *(const float4*)&Bw[(size_t)(kt + k) * HSZ + n0 + bn];
      *(float4*)&Bs[k][bn] = v;
    }
    __syncthreads();

#pragma unroll
    for (int k = 0; k < 16; ++k) {
      const float4* Ar4 = (const float4*)&As[k][0];
      const float4* Br4 = (const float4*)&Bs[k][0];
      float4 a0 = Ar4[ty];
      float4 a1 = Ar4[16 + ty];
      float4 b0 = Br4[tx];
      float4 b1 = Br4[16 + tx];
      float av[8] = {a0.x, a0.y, a0.z, a0.w, a1.x, a1.y, a1.z, a1.w};
      float bv[8] = {b0.x, b0.y, b0.z, b0.w, b1.x, b1.y, b1.z, b1.w};
#pragma unroll
      for (int i = 0; i < 8; ++i)
#pragma unroll
        for (int j = 0; j < 8; ++j)
          acc[i][j] = fmaf(av[i], bv[j], acc[i][j]);
    }
  }

  const float4 bv0 = *(const float4*)&bias[n0 + tx * 4];
  const float4 bv1 = *(const float4*)&bias[n0 + 64 + tx * 4];
#pragma unroll
  for (int i = 0; i < 8; ++i) {
    int row = m0 + ((i < 4) ? (ty * 4 + i) : (64 + ty * 4 + (i - 4)));
    float4 o0, o1;
    o0.x = acc[i][0] + bv0.x;  o0.y = acc[i][1] + bv0.y;
    o0.z = acc[i][2] + bv0.z;  o0.w = acc[i][3] + bv0.w;
    o1.x = acc[i][4] + bv1.x;  o1.y = acc[i][5] + bv1.y;
    o1.z = acc[i][6] + bv1.z;  o1.w = acc[i][7] + bv1.w;
    *(float4*)&C[(size_t)row * HSZ + n0 + tx * 4] = o0;
    *(float4*)&C[(size_t)row * HSZ + n0 + 64 + tx * 4] = o1;
  }
}

// ---------------------------------------------------------------------------
// Kernel 2: init the 64 per-WG step flags to -1 ("nothing published")
// ---------------------------------------------------------------------------
__global__ void init_cnt(int* c) { c[threadIdx.x * FLAG_STRIDE] = -1; }

// ---------------------------------------------------------------------------
// Kernel 3: persistent RNN recurrence. 64 WGs x 256 thr, 1 WG/CU (145 KB LDS).
// h exchange buffers in A-FRAGMENT layout: ull index
//   gb*4096 + kc*128 + lane*2 + (j>>2)
// where kc = col>>5 (0..31), lane = ((col>>3)&3)*16 + row, j = col&7.
// Consumer wave w lane l reads kc in [8w,8w+8) at hq + kc*128 + l*2 (+1):
// each instruction covers a contiguous 1KB frag block (16 LLC lines, vs 64
// scattered lines in the row-major layout).
// Per step t (flag[p] == s  <=>  producer p's h_s frags drained to LLC):
//   all waves: lanes poll flag (l&15) until >= t (relaxed), asm fence +
//     sched_barrier  -> no h load hoisted above observation (proven r5/r6)
//   load 8 A-frags (coalesced) -> MFMA -> Cred -> sync1
//   reduce + tanh -> hn frag store -> sync2 (per-thread vmcnt drain=release)
//   tid0: flag = t+1 (relaxed); then out store + xp prefetch (off-path)
// Overwrite safety: hn stores happen after sync1, which joins 4 waves that
// EACH observed all 16 flags >= t; flag[Y] >= t implies Y's threads drained
// their step-(t-1) loads before Y's tid0 stored the flag. Two buffers ok.
// ---------------------------------------------------------------------------
__global__ __launch_bounds__(256, 1) void rnn_persistent(
    const float* __restrict__ h_prev,   // (64, 1024) fp32
    const float* __restrict__ W,        // (1024, 1024) fp32
    float* __restrict__ out,            // (64, 512, 1024) fp32 (xp in, h out)
    ull* __restrict__ h_a,              // frag-layout ping (128 KB)
    ull* __restrict__ h_b,              // frag-layout pong (128 KB)
    int* __restrict__ cnt) {            // 64 step flags, 128B apart
  extern __shared__ char smem[];
  ushort* Wfrag = (ushort*)smem;                 // 32kc*4nt*64lane*8 = 128 KB
  float*  Cred  = (float*)(smem + 131072);       // 4 waves * 16 * 68 floats

  const int tid = threadIdx.x;
  const int gb = blockIdx.x & 3;       // batch group 0..3
  const int gn = blockIdx.x >> 2;      // col group 0..15
  const int b0 = gb * BT;
  const int n0 = gn * NT;
  int* myFlag = cnt + (gb * GRP_WGS + gn) * FLAG_STRIDE;

  // ---- one-time: W_hh column slice -> bf16 fragments in LDS ----
  for (int it = tid; it < 1024 * 16; it += 256) {
    int k  = it >> 4;
    int c4 = (it & 15) << 2;
    float4 w4 = *(const float4*)&W[(size_t)k * HSZ + n0 + c4];
    int kc = k >> 5, j = k & 7, q = (k >> 3) & 3;
    float wv[4] = {w4.x, w4.y, w4.z, w4.w};
#pragma unroll
    for (int e = 0; e < 4; ++e) {
      int n = c4 + e;
      int nt = n >> 4;
      int lane = q * 16 + (n & 15);
      Wfrag[((kc * 4 + nt) * 64 + lane) * 8 + j] = f2bf(wv[e]);
    }
  }

  // ---- one-time: OWN slice of h0 = bf16(h_prev) -> h_a (frag layout) ----
  {
    int r  = tid >> 4;                 // 0..15 row
    int c  = tid & 15;                 // 0..15 4-col group within slice
    int col4 = n0 + c * 4;
    float4 v = *(const float4*)&h_prev[(size_t)(b0 + r) * HSZ + col4];
    int kcg = gn * 2 + (c >> 3);                 // global kc of col4
    int lc  = ((c >> 1) & 3) * 16 + r;           // frag lane
    __hip_atomic_store(&h_a[(size_t)gb * 4096 + kcg * 128 + lc * 2 + (c & 1)],
                       pack4(v.x, v.y, v.z, v.w),
                       __ATOMIC_RELAXED, __HIP_MEMORY_SCOPE_AGENT);
  }

  const int w  = tid >> 6;             // wave 0..3 -> K quarter
  const int l  = tid & 63;

  // all waves poll: lane l watches group flag (l&15)
  int* pollFlag = cnt + (gb * GRP_WGS + (l & 15)) * FLAG_STRIDE;

  // epilogue mapping
  const int eb  = tid >> 4;            // 0..15 batch row
  const int en4 = (tid & 15) << 2;     // col*4 within slice
  const size_t obase = ((size_t)(b0 + eb) * SEQ) * HSZ + n0 + en4;
  // hn frag-layout index for this thread's 4 bf16 (8B)
  const int kcg_e = gn * 2 + (en4 >> 5);
  const int lc_e  = ((en4 >> 3) & 3) * 16 + eb;
  const size_t hnIdx = (size_t)gb * 4096 + kcg_e * 128 + lc_e * 2 + ((en4 & 7) >> 2);

  ull* hc = h_a;
  ull* hn = h_b;

  // prefetch xp for t=0 (no dependency on h)
  float4 xp = *(const float4*)&out[obase];

  // publish h0: barrier drains all threads' h0 stores (vmcnt0), then flag
  __syncthreads();
  if (tid == 0)
    __hip_atomic_store(myFlag, 0, __ATOMIC_RELAXED, __HIP_MEMORY_SCOPE_AGENT);

  for (int t = 0; t < SEQ; ++t) {
    // ---- acquire: every wave independently observes all 16 flags >= t ----
    while (__hip_atomic_load(pollFlag, __ATOMIC_RELAXED,
                             __HIP_MEMORY_SCOPE_AGENT) < t)
      __builtin_amdgcn_s_sleep(1);
    // no h load may be hoisted above the spin (IR + MIR fences; proven r5/r6)
    asm volatile("" ::: "memory");
    __builtin_amdgcn_sched_barrier(0);

    // ---- load this wave's 8 A-frags: COALESCED frag-layout loads ----
    Frag af[8];
    const ull* hq = hc + (size_t)gb * 4096 + (size_t)(w * 8) * 128 + l * 2;
#pragma unroll
    for (int i = 0; i < 8; ++i) {
      af[i].u2[0] = __hip_atomic_load(hq + i * 128, __ATOMIC_RELAXED,
                                      __HIP_MEMORY_SCOPE_AGENT);
      af[i].u2[1] = __hip_atomic_load(hq + i * 128 + 1, __ATOMIC_RELAXED,
                                      __HIP_MEMORY_SCOPE_AGENT);
    }

    floatx4 acc[4] = {floatx4{0.f, 0.f, 0.f, 0.f}, floatx4{0.f, 0.f, 0.f, 0.f},
                      floatx4{0.f, 0.f, 0.f, 0.f}, floatx4{0.f, 0.f, 0.f, 0.f}};
#pragma unroll
    for (int i = 0; i < 8; ++i) {
      const int kc = w * 8 + i;
#pragma unroll
      for (int nt = 0; nt < 4; ++nt) {
        short8 b8 = *(const short8*)&Wfrag[((kc * 4 + nt) * 64 + l) * 8];
        acc[nt] = __builtin_amdgcn_mfma_f32_16x16x32_bf16(af[i].s8, b8, acc[nt], 0, 0, 0);
      }
    }

    // partial C tiles -> LDS (C/D layout: col=lane&15, row=(lane>>4)*4+reg)
    {
      const int rbase = (l >> 4) * 4;
      const int cbase = l & 15;
#pragma unroll
      for (int nt = 0; nt < 4; ++nt)
#pragma unroll
        for (int r = 0; r < 4; ++r)
          Cred[(w * 16 + rbase + r) * 68 + nt * 16 + cbase] = acc[nt][r];
    }
    __syncthreads();   // sync1: joins 4 waves (each observed all 16 flags)

    // reduce 4 wave partials, tanh, publish hn frag
    float4 hv;
    {
      float4 v0 = *(const float4*)&Cred[(0 * 16 + eb) * 68 + en4];
      float4 v1 = *(const float4*)&Cred[(1 * 16 + eb) * 68 + en4];
      float4 v2 = *(const float4*)&Cred[(2 * 16 + eb) * 68 + en4];
      float4 v3 = *(const float4*)&Cred[(3 * 16 + eb) * 68 + en4];
      hv.x = fast_tanh(v0.x + v1.x + v2.x + v3.x + xp.x);
      hv.y = fast_tanh(v0.y + v1.y + v2.y + v3.y + xp.y);
      hv.z = fast_tanh(v0.z + v1.z + v2.z + v3.z + xp.z);
      hv.w = fast_tanh(v0.w + v1.w + v2.w + v3.w + xp.w);
      __hip_atomic_store(&hn[hnIdx], pack4(hv.x, hv.y, hv.z, hv.w),
                         __ATOMIC_RELAXED, __HIP_MEMORY_SCOPE_AGENT);
    }

    // sync2: (a) separates Cred read from next step's Cred write,
    // (b) release — every thread's hn store AND h loads drained (vmcnt0)
    // before tid0's flag store below. Proven mechanism (rounds 0/1/3).
    __syncthreads();
    if (tid == 0)
      __hip_atomic_store(myFlag, t + 1, __ATOMIC_RELAXED,
                         __HIP_MEMORY_SCOPE_AGENT);

    // WG-private work, off the inter-WG critical path:
    *(float4*)&out[obase + (size_t)t * HSZ] = hv;          // h_t -> out (HBM)
    if (t + 1 < SEQ)                                       // next xp prefetch
      xp = *(const float4*)&out[obase + (size_t)(t + 1) * HSZ];

    ull* tmp = hc; hc = hn; hn = tmp;
  }
}

// ---------------------------------------------------------------------------
extern "C" void kernel_launch(void* const* d_in, const int* in_sizes, int n_in,
                              void* d_out, int out_size, void* d_ws, size_t ws_size,
                              hipStream_t stream) {
  const float* inputs = (const float*)d_in[0];  // (64, 512, 512)
  const float* h_prev = (const float*)d_in[1];  // (64, 1024)
  const float* W_xh   = (const float*)d_in[2];  // (512, 1024)
  const float* W_hh   = (const float*)d_in[3];  // (1024, 1024)
  const float* b_h    = (const float*)d_in[4];  // (1024,)
  float* out = (float*)d_out;                   // (64, 512, 1024)

  int* cnt = (int*)d_ws;                        // 64 flags, 128B apart (8 KB)
  ull* h_a = (ull*)((char*)d_ws + 8192);
  ull* h_b = h_a + BATCH * 256;                 // 128 KB each (16384 ull)

  // 1. x_proj -> d_out
  dim3 g1(HSZ / 128, (BATCH * SEQ) / 128);      // (8, 256)
  xproj_gemm<<<g1, 256, 0, stream>>>(inputs, W_xh, b_h, out);

  // 2. init per-WG flags to -1
  init_cnt<<<1, 64, 0, stream>>>(cnt);

  // 3. persistent recurrence (145 KB dynamic LDS -> 1 WG/CU)
  const int smem_bytes = 131072 + 4 * 16 * 68 * (int)sizeof(float);  // 148480
  hipFuncSetAttribute((const void*)rnn_persistent,
                      hipFuncAttributeMaxDynamicSharedMemorySize, smem_bytes);
  rnn_persistent<<<NWG, 256, smem_bytes, stream>>>(h_prev, W_hh, out, h_a, h_b, cnt);
}